// Round 5
// baseline (488.815 us; speedup 1.0000x reference)
//
#include <hip/hip_runtime.h>
#include <stdint.h>

#define D_MODEL 1024
#define N_HEADS 16
#define HEAD_DIM 64
#define BATCH 4
#define SEQ 2048
#define ROWS (BATCH * SEQ)   /* 8192 */
#define K3 (3 * D_MODEL)     /* 3072 */
#define NQT (SEQ / 64)       /* 32 q-tiles of 64 */
#define SCALE_Q 0.1803368867f /* 0.125 * log2(e): QK scores land in exp2 domain */

typedef unsigned short u16;
typedef __attribute__((ext_vector_type(8))) short short8;
typedef __attribute__((ext_vector_type(4))) float floatx4;

__device__ __forceinline__ float bf2f(u16 u) {
    return __uint_as_float(((unsigned)u) << 16);
}
__device__ __forceinline__ u16 f2b(float f) {
    unsigned u = __float_as_uint(f);
    u = u + 0x7fffu + ((u >> 16) & 1u);   // RNE
    return (u16)(u >> 16);
}
__device__ __forceinline__ unsigned pk2(float a, float b) {
    return (unsigned)f2b(a) | ((unsigned)f2b(b) << 16);
}

// -------------------------------------------------- fp32 -> bf16 conversions
__global__ __launch_bounds__(256) void conv_f2b(const float* __restrict__ x,
                                                u16* __restrict__ xb, int n) {
    int i = blockIdx.x * 256 + threadIdx.x;
    if (i < n) xb[i] = f2b(x[i]);
}

__global__ __launch_bounds__(256) void transpose_f2b(const float* __restrict__ w,
                                                     u16* __restrict__ wt,
                                                     int R, int C) {
    int idx = blockIdx.x * 256 + threadIdx.x;
    if (idx >= R * C) return;
    int r = idx / C, c = idx - r * C;
    wt[(size_t)c * R + r] = f2b(w[idx]);
}

// ---------------------------------------------------------------- GEMM core
// m93-pattern: 128x128 block tile, 256 thr = 4 waves in 2x2, each wave 64x64
// (4x4 mfma 16x16x32 tiles), BK=64. LDS rows padded to 72 (2-way alias = free).
#define GEMM_CORE128(KDIM)                                                     \
    __shared__ u16 As[128][72];                                                \
    __shared__ u16 Bs[128][72];                                                \
    const int tid  = threadIdx.x;                                              \
    const int wave = tid >> 6, lane = tid & 63;                                \
    const int quad = lane >> 4, l15 = lane & 15;                               \
    const int wr = wave >> 1, wc = wave & 1;                                   \
    const int m0 = blockIdx.y * 128, n0 = blockIdx.x * 128;                    \
    const int lr = tid >> 1, lc = (tid & 1) * 32;                              \
    const u16* Ap = A + (size_t)(m0 + lr) * (KDIM) + lc;                       \
    const u16* Bp = Bt + (size_t)(n0 + lr) * (KDIM) + lc;                      \
    floatx4 acc[4][4] = {};                                                    \
    for (int k0 = 0; k0 < (KDIM); k0 += 64) {                                  \
        uint4 a0 = *(const uint4*)(Ap + k0);                                   \
        uint4 a1 = *(const uint4*)(Ap + k0 + 8);                               \
        uint4 a2 = *(const uint4*)(Ap + k0 + 16);                              \
        uint4 a3 = *(const uint4*)(Ap + k0 + 24);                              \
        uint4 b0 = *(const uint4*)(Bp + k0);                                   \
        uint4 b1 = *(const uint4*)(Bp + k0 + 8);                               \
        uint4 b2 = *(const uint4*)(Bp + k0 + 16);                              \
        uint4 b3 = *(const uint4*)(Bp + k0 + 24);                              \
        __syncthreads();                                                       \
        *(uint4*)&As[lr][lc]      = a0;                                        \
        *(uint4*)&As[lr][lc + 8]  = a1;                                        \
        *(uint4*)&As[lr][lc + 16] = a2;                                        \
        *(uint4*)&As[lr][lc + 24] = a3;                                        \
        *(uint4*)&Bs[lr][lc]      = b0;                                        \
        *(uint4*)&Bs[lr][lc + 8]  = b1;                                        \
        *(uint4*)&Bs[lr][lc + 16] = b2;                                        \
        *(uint4*)&Bs[lr][lc + 24] = b3;                                        \
        __syncthreads();                                                       \
        _Pragma("unroll")                                                      \
        for (int ks = 0; ks < 2; ++ks) {                                       \
            const int kk = ks * 32 + quad * 8;                                 \
            short8 af[4], bf[4];                                               \
            _Pragma("unroll")                                                  \
            for (int t = 0; t < 4; ++t) {                                      \
                af[t] = *(const short8*)&As[wr * 64 + t * 16 + l15][kk];       \
                bf[t] = *(const short8*)&Bs[wc * 64 + t * 16 + l15][kk];       \
            }                                                                  \
            _Pragma("unroll")                                                  \
            for (int i = 0; i < 4; ++i)                                        \
                _Pragma("unroll")                                              \
                for (int j = 0; j < 4; ++j)                                    \
                    acc[i][j] = __builtin_amdgcn_mfma_f32_16x16x32_bf16(       \
                        af[i], bf[j], acc[i][j], 0, 0, 0);                     \
        }                                                                      \
    }

// GEMM1: xb @ wqkv -> q (pre-scaled by SCALE_Q), k as [BH][T][64];
//        v TRANSPOSED as [BH][64][T]
__global__ __launch_bounds__(256) void gemm_qkv(const u16* __restrict__ A,
                                                const u16* __restrict__ Bt,
                                                u16* __restrict__ qo,
                                                u16* __restrict__ ko,
                                                u16* __restrict__ vo) {
    GEMM_CORE128(D_MODEL)
    #pragma unroll
    for (int i = 0; i < 4; ++i)
        #pragma unroll
        for (int j = 0; j < 4; ++j) {
            const int col   = n0 + wc * 64 + j * 16 + l15;
            const int rb    = m0 + wr * 64 + i * 16 + quad * 4;
            const int which = col >> 10;
            const int cc    = col & 1023;
            const int h = cc >> 6, d = cc & 63;
            #pragma unroll
            for (int rr = 0; rr < 4; ++rr) {
                const int row = rb + rr;
                const int b = row >> 11, t = row & 2047;
                if (which == 0)
                    qo[(((size_t)(b * N_HEADS + h)) * SEQ + t) * HEAD_DIM + d] =
                        f2b(acc[i][j][rr] * SCALE_Q);
                else if (which == 1)
                    ko[(((size_t)(b * N_HEADS + h)) * SEQ + t) * HEAD_DIM + d] =
                        f2b(acc[i][j][rr]);
                else
                    vo[(((size_t)(b * N_HEADS + h)) * HEAD_DIM + d) * SEQ + t] =
                        f2b(acc[i][j][rr]);
            }
        }
}

// GEMM2: attn_out[8192][1024] @ wproj + bias -> d_out fp32
__global__ __launch_bounds__(256) void gemm_proj(const u16* __restrict__ A,
                                                 const u16* __restrict__ Bt,
                                                 const float* __restrict__ bias,
                                                 float* __restrict__ out) {
    GEMM_CORE128(D_MODEL)
    #pragma unroll
    for (int i = 0; i < 4; ++i)
        #pragma unroll
        for (int j = 0; j < 4; ++j) {
            const int col = n0 + wc * 64 + j * 16 + l15;
            const int rb  = m0 + wr * 64 + i * 16 + quad * 4;
            const float bv = bias[col];
            #pragma unroll
            for (int rr = 0; rr < 4; ++rr) {
                const int row = rb + rr;
                out[(size_t)row * D_MODEL + col] = acc[i][j][rr] + bv;
            }
        }
}

// ------------------------------------------------------- MFMA flash attention
// S^T = K.Q^T: lane l15 = query, (quad,reg) = key; per-lane softmax state.
// Q pre-scaled by 0.125*log2e in GEMM1 -> scores in exp2 domain (native
// v_exp_f32, no mul). Main loop over full chunks is mask-free and
// branch-free; K for chunk c+1 prefetched right after chunk c's QK consumes
// the regs. Diagonal chunk handled separately after the loop (its K is the
// last prefetch). Per-lane l, reduced across quads once at the end.
// Work balance: block = q-tile pair (NQT-1-p, p), grid (16, 64).
__global__ __launch_bounds__(256, 4) void attn_mfma(const u16* __restrict__ q,
                                                    const u16* __restrict__ k,
                                                    const u16* __restrict__ vt,
                                                    u16* __restrict__ o) {
    __shared__ u16 Plds[4][16][72];
    const int tid = threadIdx.x;
    const int w = tid >> 6, lane = tid & 63;
    const int quad = lane >> 4, l15 = lane & 15;
    const int bh = blockIdx.y;
    const int b = bh >> 4, h = bh & 15;
    const u16* kb  = k  + (size_t)bh * SEQ * HEAD_DIM;
    const u16* vtb = vt + (size_t)bh * HEAD_DIM * SEQ;

    #pragma unroll 1
    for (int seg = 0; seg < 2; ++seg) {
        const int qt = seg ? (int)blockIdx.x : (NQT - 1 - (int)blockIdx.x);
        const int qrow = qt * 64 + w * 16 + l15;
        const u16* qp = q + ((size_t)bh * SEQ + qrow) * HEAD_DIM + quad * 8;
        const short8 bq0 = *(const short8*)(qp);
        const short8 bq1 = *(const short8*)(qp + 32);

        floatx4 O[4] = {};
        float m = -1e30f, l = 0.f;

        // preload K chunk 0
        short8 kf0[4], kf1[4];
        #pragma unroll
        for (int kt = 0; kt < 4; ++kt) {
            const u16* kp = kb + ((size_t)(kt * 16 + l15)) * HEAD_DIM + quad * 8;
            kf0[kt] = *(const short8*)kp;
            kf1[kt] = *(const short8*)(kp + 32);
        }

        // ---------------- main loop: full 64-key chunks, no masking
        #pragma unroll 2
        for (int c = 0; c < qt; ++c) {
            floatx4 s[4];
            #pragma unroll
            for (int kt = 0; kt < 4; ++kt) {
                floatx4 z = {};
                z = __builtin_amdgcn_mfma_f32_16x16x32_bf16(kf0[kt], bq0, z, 0, 0, 0);
                z = __builtin_amdgcn_mfma_f32_16x16x32_bf16(kf1[kt], bq1, z, 0, 0, 0);
                s[kt] = z;
            }
            // prefetch K for chunk c+1 (possibly the diagonal)
            #pragma unroll
            for (int kt = 0; kt < 4; ++kt) {
                const u16* kp = kb + ((size_t)((c + 1) * 64 + kt * 16 + l15)) * HEAD_DIM + quad * 8;
                kf0[kt] = *(const short8*)kp;
                kf1[kt] = *(const short8*)(kp + 32);
            }
            // per-lane max over 16 scores, reduce across quads
            float cm = s[0][0];
            #pragma unroll
            for (int kt = 0; kt < 4; ++kt) {
                cm = fmaxf(cm, s[kt][0]); cm = fmaxf(cm, s[kt][1]);
                cm = fmaxf(cm, s[kt][2]); cm = fmaxf(cm, s[kt][3]);
            }
            cm = fmaxf(cm, __shfl_xor(cm, 16));
            cm = fmaxf(cm, __shfl_xor(cm, 32));
            const float nm    = fmaxf(m, cm);
            const float alpha = exp2f(m - nm);
            m = nm;
            float ls = 0.f;
            #pragma unroll
            for (int kt = 0; kt < 4; ++kt) {
                float p0 = exp2f(s[kt][0] - nm);
                float p1 = exp2f(s[kt][1] - nm);
                float p2 = exp2f(s[kt][2] - nm);
                float p3 = exp2f(s[kt][3] - nm);
                ls += (p0 + p1) + (p2 + p3);
                uint2 pkv;
                pkv.x = pk2(p0, p1);
                pkv.y = pk2(p2, p3);
                *(uint2*)&Plds[w][l15][kt * 16 + quad * 4] = pkv;
            }
            l = l * alpha + ls;
            #pragma unroll
            for (int dt = 0; dt < 4; ++dt) {
                O[dt][0] *= alpha; O[dt][1] *= alpha;
                O[dt][2] *= alpha; O[dt][3] *= alpha;
            }
            short8 pb0 = *(const short8*)&Plds[w][l15][quad * 8];
            short8 pb1 = *(const short8*)&Plds[w][l15][32 + quad * 8];
            #pragma unroll
            for (int dt = 0; dt < 4; ++dt) {
                const u16* vp = vtb + ((size_t)(dt * 16 + l15)) * SEQ + c * 64 + quad * 8;
                short8 av0 = *(const short8*)vp;
                short8 av1 = *(const short8*)(vp + 32);
                O[dt] = __builtin_amdgcn_mfma_f32_16x16x32_bf16(av0, pb0, O[dt], 0, 0, 0);
                O[dt] = __builtin_amdgcn_mfma_f32_16x16x32_bf16(av1, pb1, O[dt], 0, 0, 0);
            }
        }

        // ---------------- diagonal chunk c == qt (K already in kf)
        {
            const int c = qt;
            const int ntiles = w + 1;            // wave-uniform
            const int nhalf  = (w >> 1) + 1;
            float pv[4][4];
            float cm = -1e30f;
            #pragma unroll
            for (int kt = 0; kt < 4; ++kt) {
                if (kt < ntiles) {
                    floatx4 z = {};
                    z = __builtin_amdgcn_mfma_f32_16x16x32_bf16(kf0[kt], bq0, z, 0, 0, 0);
                    z = __builtin_amdgcn_mfma_f32_16x16x32_bf16(kf1[kt], bq1, z, 0, 0, 0);
                    #pragma unroll
                    for (int r = 0; r < 4; ++r) {
                        float sv = z[r];
                        if (kt == w && quad * 4 + r > l15) sv = -1e30f;
                        pv[kt][r] = sv;
                        cm = fmaxf(cm, sv);
                    }
                }
            }
            cm = fmaxf(cm, __shfl_xor(cm, 16));
            cm = fmaxf(cm, __shfl_xor(cm, 32));
            const float nm    = fmaxf(m, cm);
            const float alpha = exp2f(m - nm);
            m = nm;
            float ls = 0.f;
            #pragma unroll
            for (int kt = 0; kt < 4; ++kt) {
                if (kt < ntiles) {
                    float p0 = exp2f(pv[kt][0] - nm);
                    float p1 = exp2f(pv[kt][1] - nm);
                    float p2 = exp2f(pv[kt][2] - nm);
                    float p3 = exp2f(pv[kt][3] - nm);
                    ls += (p0 + p1) + (p2 + p3);
                    uint2 pkv;
                    pkv.x = pk2(p0, p1);
                    pkv.y = pk2(p2, p3);
                    *(uint2*)&Plds[w][l15][kt * 16 + quad * 4] = pkv;
                } else if (kt < nhalf * 2) {
                    uint2 z2; z2.x = 0; z2.y = 0;
                    *(uint2*)&Plds[w][l15][kt * 16 + quad * 4] = z2;
                }
            }
            l = l * alpha + ls;
            #pragma unroll
            for (int dt = 0; dt < 4; ++dt) {
                O[dt][0] *= alpha; O[dt][1] *= alpha;
                O[dt][2] *= alpha; O[dt][3] *= alpha;
            }
            short8 pb0 = *(const short8*)&Plds[w][l15][quad * 8];
            #pragma unroll
            for (int dt = 0; dt < 4; ++dt) {
                const u16* vp = vtb + ((size_t)(dt * 16 + l15)) * SEQ + c * 64 + quad * 8;
                short8 av0 = *(const short8*)vp;
                O[dt] = __builtin_amdgcn_mfma_f32_16x16x32_bf16(av0, pb0, O[dt], 0, 0, 0);
            }
            if (nhalf == 2) {
                short8 pb1 = *(const short8*)&Plds[w][l15][32 + quad * 8];
                #pragma unroll
                for (int dt = 0; dt < 4; ++dt) {
                    const u16* vp = vtb + ((size_t)(dt * 16 + l15)) * SEQ + c * 64 + 32 + quad * 8;
                    short8 av1 = *(const short8*)vp;
                    O[dt] = __builtin_amdgcn_mfma_f32_16x16x32_bf16(av1, pb1, O[dt], 0, 0, 0);
                }
            }
        }

        // ---------------- epilogue
        l += __shfl_xor(l, 16);
        l += __shfl_xor(l, 32);
        const float inv = 1.f / l;
        u16* op = o + ((size_t)(b * SEQ + qrow)) * D_MODEL + h * 64 + quad * 4;
        #pragma unroll
        for (int dt = 0; dt < 4; ++dt) {
            uint2 pkv;
            pkv.x = pk2(O[dt][0] * inv, O[dt][1] * inv);
            pkv.y = pk2(O[dt][2] * inv, O[dt][3] * inv);
            *(uint2*)(op + dt * 16) = pkv;
        }
    }
}

// ---------------------------------------------------------------- launch
extern "C" void kernel_launch(void* const* d_in, const int* in_sizes, int n_in,
                              void* d_out, int out_size, void* d_ws, size_t ws_size,
                              hipStream_t stream) {
    const float* x      = (const float*)d_in[0];
    const float* w_qkv  = (const float*)d_in[1];
    const float* w_proj = (const float*)d_in[2];
    const float* b_proj = (const float*)d_in[3];
    float* out = (float*)d_out;

    u16* xb      = (u16*)d_ws;                                 // [8192][1024]
    u16* wt_qkv  = xb + (size_t)ROWS * D_MODEL;                // [3072][1024]
    u16* wt_proj = wt_qkv + (size_t)D_MODEL * K3;              // [1024][1024]
    u16* qws     = wt_proj + (size_t)D_MODEL * D_MODEL;        // [BH][T][64] (pre-scaled)
    u16* kws     = qws + (size_t)ROWS * D_MODEL;               // [BH][T][64]
    u16* vws     = kws + (size_t)ROWS * D_MODEL;               // [BH][64][T]
    u16* aout    = vws + (size_t)ROWS * D_MODEL;               // [8192][1024]

    conv_f2b<<<(ROWS * D_MODEL + 255) / 256, 256, 0, stream>>>(x, xb, ROWS * D_MODEL);
    transpose_f2b<<<(D_MODEL * K3 + 255) / 256, 256, 0, stream>>>(w_qkv, wt_qkv, D_MODEL, K3);
    transpose_f2b<<<(D_MODEL * D_MODEL + 255) / 256, 256, 0, stream>>>(w_proj, wt_proj, D_MODEL, D_MODEL);

    gemm_qkv<<<dim3(K3 / 128, ROWS / 128), 256, 0, stream>>>(xb, wt_qkv, qws, kws, vws);

    attn_mfma<<<dim3(NQT / 2, BATCH * N_HEADS), 256, 0, stream>>>(qws, kws, vws, aout);

    gemm_proj<<<dim3(D_MODEL / 128, ROWS / 128), 256, 0, stream>>>(aout, wt_proj, b_proj, out);
}